// Round 8
// baseline (127.749 us; speedup 1.0000x reference)
//
#include <hip/hip_runtime.h>
#include <math.h>

#define NB      8192
#define HLEN    200
#define DIM     128
#define AH      64
#define NITEMS  100000
#define NTILE   13
#define WTILES  7              // tiles per wave (2 waves per batch element)
#define GRP_BLKS (NB / 4)
#define CONV_BLKS 1024

typedef __attribute__((ext_vector_type(4))) float f32x4;
typedef __attribute__((ext_vector_type(2))) float f32x2;
typedef __attribute__((ext_vector_type(4))) int   i32x4;
typedef __attribute__((ext_vector_type(8))) short bf16x8;
typedef unsigned int uint;

__device__ __forceinline__ unsigned short f2bf(float f) {
  uint u = __float_as_uint(f);
  u += 0x7fffu + ((u >> 16) & 1u);
  return (unsigned short)(u >> 16);
}
__device__ __forceinline__ float bf2f(unsigned short h) {
  return __uint_as_float(((uint)h) << 16);
}
__device__ __forceinline__ long pick64(const i32x4& v, int h) {
  return (long)(unsigned)v[2 * h] | ((long)(unsigned)v[2 * h + 1] << 32);
}
__device__ __forceinline__ i32x4 ldnt(const void* p) {
  return __builtin_nontemporal_load((const i32x4*)p);
}

// ---------------------------------------------------------------------------
// Pre-kernel (unchanged from r7: pre ≈ 22us). Blocks [0, GRP_BLKS): bilinear
// interaction + item copy, one 4-batch group per block. Blocks [GRP_BLKS,+):
// item_table f32 -> fp8 e4m3 + w1 -> fp8 fragment table (r2 layout).
// ---------------------------------------------------------------------------
__global__ __launch_bounds__(256)
void pre_kernel(const int* __restrict__ user_ids,
                const int* __restrict__ item_ids,
                const float* __restrict__ user_table,
                const float* __restrict__ item_table,
                const float* __restrict__ fi,
                const float* __restrict__ w1,
                unsigned char* __restrict__ tbl8,
                unsigned char* __restrict__ w1f8,
                float* __restrict__ out_item,
                float* __restrict__ out_inter) {
  const int t = threadIdx.x;
  if (blockIdx.x < GRP_BLKS) {
    __shared__ unsigned short fitb[DIM * 130];
    __shared__ float u4[4][DIM];
    __shared__ float red[4][4];
    for (int i = t; i < DIM * DIM; i += 256) {
      int d = i >> 7, e = i & 127;
      fitb[e * 130 + d] = f2bf(fi[i]);
    }
    const int col = t & 127;
    const int dh = t >> 7;
    const int lane = t & 63;
    const int wv = t >> 6;
    const int bb = blockIdx.x * 4;
    for (int i = t; i < 4 * DIM; i += 256) {
      int bi = i >> 7, d = i & 127;
      u4[bi][d] = user_table[(long)user_ids[bb + bi] * DIM + d];
    }
    __syncthreads();
    const unsigned short* fr = &fitb[col * 130 + dh * 64];
    float a0 = 0.f, a1 = 0.f, a2 = 0.f, a3 = 0.f;
#pragma unroll 4
    for (int d = 0; d < 64; d += 4) {
      float f0 = bf2f(fr[d]), f1 = bf2f(fr[d + 1]), f2 = bf2f(fr[d + 2]), f3 = bf2f(fr[d + 3]);
      f32x4 q0 = *(const f32x4*)&u4[0][dh * 64 + d];
      f32x4 q1 = *(const f32x4*)&u4[1][dh * 64 + d];
      f32x4 q2 = *(const f32x4*)&u4[2][dh * 64 + d];
      f32x4 q3 = *(const f32x4*)&u4[3][dh * 64 + d];
      a0 = fmaf(f0, q0[0], a0); a0 = fmaf(f1, q0[1], a0); a0 = fmaf(f2, q0[2], a0); a0 = fmaf(f3, q0[3], a0);
      a1 = fmaf(f0, q1[0], a1); a1 = fmaf(f1, q1[1], a1); a1 = fmaf(f2, q1[2], a1); a1 = fmaf(f3, q1[3], a1);
      a2 = fmaf(f0, q2[0], a2); a2 = fmaf(f1, q2[1], a2); a2 = fmaf(f2, q2[2], a2); a2 = fmaf(f3, q2[3], a2);
      a3 = fmaf(f0, q3[0], a3); a3 = fmaf(f1, q3[1], a3); a3 = fmaf(f2, q3[2], a3); a3 = fmaf(f3, q3[3], a3);
    }
    const float vv0 = item_table[(long)item_ids[bb + 0] * DIM + col];
    const float vv1 = item_table[(long)item_ids[bb + 1] * DIM + col];
    const float vv2 = item_table[(long)item_ids[bb + 2] * DIM + col];
    const float vv3 = item_table[(long)item_ids[bb + 3] * DIM + col];
    if (dh == 0) {
      out_item[(long)(bb + 0) * DIM + col] = vv0;
      out_item[(long)(bb + 1) * DIM + col] = vv1;
      out_item[(long)(bb + 2) * DIM + col] = vv2;
      out_item[(long)(bb + 3) * DIM + col] = vv3;
    }
    float p0 = a0 * vv0, p1 = a1 * vv1, p2 = a2 * vv2, p3 = a3 * vv3;
#pragma unroll
    for (int msk = 1; msk <= 32; msk <<= 1) {
      p0 += __shfl_xor(p0, msk);
      p1 += __shfl_xor(p1, msk);
      p2 += __shfl_xor(p2, msk);
      p3 += __shfl_xor(p3, msk);
    }
    if (lane == 0) { red[wv][0] = p0; red[wv][1] = p1; red[wv][2] = p2; red[wv][3] = p3; }
    __syncthreads();
    if (t < 4)
      out_inter[bb + t] = red[0][t] + red[1][t] + red[2][t] + red[3][t];
  } else {
    const int cb = blockIdx.x - GRP_BLKS;
    const long t0 = (long)cb * 256 + t;
    const long total4 = (long)NITEMS * DIM / 4;
    const long stride = (long)CONV_BLKS * 256;
    for (long i = t0; i < total4; i += stride) {
      f32x4 v = ((const f32x4*)item_table)[i];
      int p = __builtin_amdgcn_cvt_pk_fp8_f32(v[0], v[1], 0, false);
      p     = __builtin_amdgcn_cvt_pk_fp8_f32(v[2], v[3], p, true);
      ((int*)tbl8)[i] = p;
    }
    if (t0 < 16384) {
      int L = (int)t0;
      int j = L & 7, gg = (L >> 3) & 3, mm = (L >> 5) & 15;
      int nt = (L >> 9) & 3, s = (L >> 11) & 3, part = (L >> 13) & 1;
      int kg = part * 128 + (s >> 1) * 64 + gg * 16 + (s & 1) * 8 + j;
      float v = w1[kg * AH + nt * 16 + mm];
      int pk = __builtin_amdgcn_cvt_pk_fp8_f32(v, v, 0, false);
      w1f8[L] = (unsigned char)(pk & 0xff);
    }
  }
}

// ---------------------------------------------------------------------------
// Main kernel: r2-verified fp8 body, TWO waves per batch element.
// Wave h in {0,1} of each b handles tiles h*7 .. h*7+6 (tile 13 fully
// masked). Register gather ring: 4 buffers, distance 3. Partial repr
// combined via 1KB LDS + one block barrier. f32x2 packed accumulate.
// ---------------------------------------------------------------------------
__global__ __launch_bounds__(256, 4)
void main_kernel_fp8(const int* __restrict__ user_ids,
                     const int* __restrict__ user_history,
                     const float* __restrict__ user_table,
                     const unsigned char* __restrict__ tbl8,
                     const unsigned char* __restrict__ w1f8,
                     const float* __restrict__ b1,
                     const float* __restrict__ w2,
                     const float* __restrict__ b2,
                     float* __restrict__ out_user) {
  __shared__ float comb[2][128];
  const int lane = threadIdx.x & 63;
  const int wave = threadIdx.x >> 6;
  const int bslot = wave >> 1;       // which of the 2 batch elems in block
  const int h = wave & 1;            // which half of the history
  const int b = blockIdx.x * 2 + bslot;
  const int m = lane & 15;
  const int g = lane >> 4;

  const int uid = __builtin_amdgcn_readfirstlane(user_ids[b]);
  const float* urow = user_table + (long)uid * DIM;
  const int* hrow = user_history + (long)b * HLEN;

  // ---- this wave's 7 history indices (rows (h*7+t)*16 + m) ----
  int idxs[WTILES];
#pragma unroll
  for (int t = 0; t < WTILES; ++t) {
    int row = (h * WTILES + t) * 16 + m;
    idxs[t] = (row < HLEN) ? hrow[row] : 0;
  }

  // ---- gather ring: 4 buffers, distance 3; first 3 issued immediately ----
  i32x4 pa[4][2];
#define LOADT(T, BUF)                                                          \
  {                                                                            \
    const unsigned char* p_ = tbl8 + ((long)idxs[T] << 7) + g * 16;            \
    pa[BUF][0] = ldnt(p_);                                                     \
    pa[BUF][1] = ldnt(p_ + 64);                                                \
  }
  LOADT(0, 0) LOADT(1, 1) LOADT(2, 2)

  // ---- u -> fp8 A-fragments (same (g,byte)->k map as history rows) ----
  i32x4 uf[2];
#pragma unroll
  for (int kb = 0; kb < 2; ++kb) {
    const float* up = urow + kb * 64 + g * 16;
    f32x4 q0 = *(const f32x4*)(up + 0);
    f32x4 q1 = *(const f32x4*)(up + 4);
    f32x4 q2 = *(const f32x4*)(up + 8);
    f32x4 q3 = *(const f32x4*)(up + 12);
    i32x4 d;
    d[0] = __builtin_amdgcn_cvt_pk_fp8_f32(q0[0], q0[1], 0, false);
    d[0] = __builtin_amdgcn_cvt_pk_fp8_f32(q0[2], q0[3], d[0], true);
    d[1] = __builtin_amdgcn_cvt_pk_fp8_f32(q1[0], q1[1], 0, false);
    d[1] = __builtin_amdgcn_cvt_pk_fp8_f32(q1[2], q1[3], d[1], true);
    d[2] = __builtin_amdgcn_cvt_pk_fp8_f32(q2[0], q2[1], 0, false);
    d[2] = __builtin_amdgcn_cvt_pk_fp8_f32(q2[2], q2[3], d[2], true);
    d[3] = __builtin_amdgcn_cvt_pk_fp8_f32(q3[0], q3[1], 0, false);
    d[3] = __builtin_amdgcn_cvt_pk_fp8_f32(q3[2], q3[3], d[3], true);
    uf[kb] = d;
  }

  const unsigned char* wtop = w1f8;
  const unsigned char* wbot = w1f8 + 8192;

  // ---- u-projection via MFMA: ubreg = (u @ w1_top)[nt*16+m] + b1 ----
  f32x4 accu[4];
#pragma unroll
  for (int nt = 0; nt < 4; ++nt) accu[nt] = (f32x4){0.f, 0.f, 0.f, 0.f};
#pragma unroll
  for (int s = 0; s < 4; ++s) {
    long a_s = pick64(uf[s >> 1], s & 1);
#pragma unroll
    for (int nt = 0; nt < 4; ++nt) {
      long bf = *(const long*)(wtop + ((s * 4 + nt) * 16 + m) * 32 + g * 8);
      accu[nt] = __builtin_amdgcn_mfma_f32_16x16x32_fp8_fp8(a_s, bf, accu[nt], 0, 0, 0);
    }
  }
  float ubreg[4], w2reg[4];
#pragma unroll
  for (int nt = 0; nt < 4; ++nt) {
    ubreg[nt] = accu[nt][0] + b1[nt * 16 + m];
    w2reg[nt] = w2[nt * 16 + m];
  }
  const float b2v = b2[0];

  // ---- W1 bottom fragments, held in registers (16 x 8B) ----
  long bfr[4][4];
#pragma unroll
  for (int s = 0; s < 4; ++s)
#pragma unroll
    for (int nt = 0; nt < 4; ++nt)
      bfr[s][nt] = *(const long*)(wbot + ((s * 4 + nt) * 16 + m) * 32 + g * 8);

  f32x2 arep2[16];
#pragma unroll
  for (int c = 0; c < 16; ++c) arep2[c] = (f32x2){0.f, 0.f};

  // ---- 7-tile pipelined loop ----
#pragma unroll
  for (int t = 0; t < WTILES; ++t) {
    if (t + 3 < WTILES) LOADT(t + 3, (t + 3) & 3)
    const int cb = t & 3;

    f32x4 acc[4];
#pragma unroll
    for (int nt = 0; nt < 4; ++nt) acc[nt] = (f32x4){0.f, 0.f, 0.f, 0.f};
#pragma unroll
    for (int s = 0; s < 4; ++s) {
      long a_s = pick64(pa[cb][s >> 1], s & 1);
#pragma unroll
      for (int nt = 0; nt < 4; ++nt)
        acc[nt] = __builtin_amdgcn_mfma_f32_16x16x32_fp8_fp8(a_s, bfr[s][nt], acc[nt], 0, 0, 0);
    }

    // scores: acc[nt][r] = S[row=g*4+r][col=nt*16+m]; reduce over 16 lanes
    float sums[4];
#pragma unroll
    for (int r = 0; r < 4; ++r) {
      float s = 0.f;
#pragma unroll
      for (int nt = 0; nt < 4; ++nt) {
        float hh = fmaxf(acc[nt][r] + ubreg[nt], 0.f);
        s = fmaf(hh, w2reg[nt], s);
      }
      s += __shfl_xor(s, 1);
      s += __shfl_xor(s, 2);
      s += __shfl_xor(s, 4);
      s += __shfl_xor(s, 8);
      sums[r] = s;
    }
    const int q = m & 3;
    float keep = (q == 0) ? sums[0] : (q == 1) ? sums[1] : (q == 2) ? sums[2] : sums[3];
    float sv = __shfl(keep, ((m >> 2) << 4) | m);
    float attw = 1.f / (1.f + __expf(-(sv + b2v)));
    if ((h * WTILES + t) * 16 + m >= HLEN) attw = 0.f;
    const f32x2 aw2 = (f32x2){attw, attw};

    // packed attention-weighted accumulate (f32x2 -> v_pk_fma_f32)
#pragma unroll
    for (int kb = 0; kb < 2; ++kb)
#pragma unroll
      for (int d = 0; d < 4; ++d) {
        f32x2 lo = __builtin_amdgcn_cvt_pk_f32_fp8(pa[cb][kb][d], false);
        f32x2 hi = __builtin_amdgcn_cvt_pk_f32_fp8(pa[cb][kb][d], true);
        const int base = kb * 8 + d * 2;
        arep2[base + 0] = arep2[base + 0] + aw2 * lo;
        arep2[base + 1] = arep2[base + 1] + aw2 * hi;
      }
  }
#undef LOADT

  // reduce over the 16 row-lanes of each group
#pragma unroll
  for (int c = 0; c < 16; ++c) {
#pragma unroll
    for (int e = 0; e < 2; ++e) {
      float v = arep2[c][e];
      v += __shfl_xor(v, 1);
      v += __shfl_xor(v, 2);
      v += __shfl_xor(v, 4);
      v += __shfl_xor(v, 8);
      arep2[c][e] = v;
    }
  }

  // ---- combine the two half-history partials via LDS ----
  if (h == 1 && m == 0) {
#pragma unroll
    for (int c = 0; c < 16; ++c) {
      comb[bslot][g * 32 + 2 * c + 0] = arep2[c][0];
      comb[bslot][g * 32 + 2 * c + 1] = arep2[c][1];
    }
  }
  __syncthreads();
  if (h == 0 && m == 0) {
    // arep flat index c2 = kb*16 + i4*4 + qq  <->  col = kb*64 + g*16 + i4*4 + qq
#pragma unroll
    for (int kb = 0; kb < 2; ++kb)
#pragma unroll
      for (int i4 = 0; i4 < 4; ++i4) {
        const int col = kb * 64 + g * 16 + i4 * 4;
        f32x4 uv = *(const f32x4*)(urow + col);
        f32x4 o;
#pragma unroll
        for (int qq = 0; qq < 4; ++qq) {
          const int c2 = kb * 16 + i4 * 4 + qq;
          o[qq] = uv[qq] + arep2[c2 >> 1][c2 & 1] + comb[bslot][g * 32 + c2];
        }
        *(f32x4*)(out_user + (long)b * DIM + col) = o;
      }
  }
}

// ---------------------------------------------------------------------------
// Fallback (ws too small): r1 bf16-inline path, f32 table reads (verified).
// ---------------------------------------------------------------------------
__global__ __launch_bounds__(256)
void main_fallback(const int* __restrict__ user_ids,
                   const int* __restrict__ user_history,
                   const float* __restrict__ user_table,
                   const float* __restrict__ item_table,
                   const float* __restrict__ w1,
                   const float* __restrict__ b1,
                   const float* __restrict__ w2,
                   const float* __restrict__ b2,
                   float* __restrict__ out_user) {
  const int lane = threadIdx.x & 63;
  const int wave = threadIdx.x >> 6;
  const int b = blockIdx.x * 4 + wave;
  const int m = lane & 15, g = lane >> 4;
  const int uid = __builtin_amdgcn_readfirstlane(user_ids[b]);
  const float* urow = user_table + (long)uid * DIM;
  float upj = b1[lane];
#pragma unroll 8
  for (int d = 0; d < DIM; ++d) upj = fmaf(urow[d], w1[d * AH + lane], upj);
  bf16x8 bfr[4][4];
#pragma unroll
  for (int ks = 0; ks < 4; ++ks)
#pragma unroll
    for (int nt = 0; nt < 4; ++nt) {
      bf16x8 bv;
#pragma unroll
      for (int j = 0; j < 8; ++j)
        bv[j] = (short)f2bf(w1[(DIM + ks * 32 + g * 8 + j) * AH + nt * 16 + m]);
      bfr[ks][nt] = bv;
    }
  float ubreg[4], w2reg[4];
#pragma unroll
  for (int nt = 0; nt < 4; ++nt) {
    ubreg[nt] = __shfl(upj, nt * 16 + m);
    w2reg[nt] = w2[nt * 16 + m];
  }
  const float b2v = b2[0];
  float arep[32];
#pragma unroll
  for (int c = 0; c < 32; ++c) arep[c] = 0.f;
  const int* hrow = user_history + (long)b * HLEN;
  for (int t = 0; t < NTILE; ++t) {
    const int row = t * 16 + m;
    const int idx = (row < HLEN) ? hrow[row] : 0;
    bf16x8 a[4];
    const float* rp = item_table + (long)idx * DIM;
#pragma unroll
    for (int ks = 0; ks < 4; ++ks) {
      f32x4 lo = *(const f32x4*)(rp + ks * 32 + g * 8);
      f32x4 hi = *(const f32x4*)(rp + ks * 32 + g * 8 + 4);
      bf16x8 av;
      av[0] = (short)f2bf(lo[0]); av[1] = (short)f2bf(lo[1]);
      av[2] = (short)f2bf(lo[2]); av[3] = (short)f2bf(lo[3]);
      av[4] = (short)f2bf(hi[0]); av[5] = (short)f2bf(hi[1]);
      av[6] = (short)f2bf(hi[2]); av[7] = (short)f2bf(hi[3]);
      a[ks] = av;
    }
    f32x4 acc[4];
#pragma unroll
    for (int nt = 0; nt < 4; ++nt) acc[nt] = (f32x4){0.f, 0.f, 0.f, 0.f};
#pragma unroll
    for (int ks = 0; ks < 4; ++ks)
#pragma unroll
      for (int nt = 0; nt < 4; ++nt)
        acc[nt] = __builtin_amdgcn_mfma_f32_16x16x32_bf16(a[ks], bfr[ks][nt], acc[nt], 0, 0, 0);
    float sums[4];
#pragma unroll
    for (int r = 0; r < 4; ++r) {
      float s = 0.f;
#pragma unroll
      for (int nt = 0; nt < 4; ++nt) {
        float hh = fmaxf(acc[nt][r] + ubreg[nt], 0.f);
        s = fmaf(hh, w2reg[nt], s);
      }
      s += __shfl_xor(s, 1); s += __shfl_xor(s, 2);
      s += __shfl_xor(s, 4); s += __shfl_xor(s, 8);
      sums[r] = s;
    }
    const int q = m & 3;
    float keep = (q == 0) ? sums[0] : (q == 1) ? sums[1] : (q == 2) ? sums[2] : sums[3];
    float sv = __shfl(keep, ((m >> 2) << 4) | m);
    float attw = 1.f / (1.f + __expf(-(sv + b2v)));
    if (row >= HLEN) attw = 0.f;
#pragma unroll
    for (int ks = 0; ks < 4; ++ks)
#pragma unroll
      for (int j = 0; j < 8; ++j)
        arep[ks * 8 + j] = fmaf(attw, bf2f((unsigned short)a[ks][j]), arep[ks * 8 + j]);
  }
#pragma unroll
  for (int c = 0; c < 32; ++c) {
    arep[c] += __shfl_xor(arep[c], 1);
    arep[c] += __shfl_xor(arep[c], 2);
    arep[c] += __shfl_xor(arep[c], 4);
    arep[c] += __shfl_xor(arep[c], 8);
  }
  if (m == 0) {
#pragma unroll
    for (int ks = 0; ks < 4; ++ks)
#pragma unroll
      for (int j = 0; j < 8; ++j) {
        const int col = ks * 32 + g * 8 + j;
        out_user[(long)b * DIM + col] = urow[col] + arep[ks * 8 + j];
      }
  }
}

// ---------------------------------------------------------------------------
extern "C" void kernel_launch(void* const* d_in, const int* in_sizes, int n_in,
                              void* d_out, int out_size, void* d_ws, size_t ws_size,
                              hipStream_t stream) {
  const int*   user_ids     = (const int*)d_in[0];
  const int*   item_ids     = (const int*)d_in[1];
  const int*   user_history = (const int*)d_in[2];
  const float* user_table   = (const float*)d_in[3];
  const float* item_table   = (const float*)d_in[4];
  const float* fi           = (const float*)d_in[5];
  const float* w1           = (const float*)d_in[6];
  const float* b1           = (const float*)d_in[7];
  const float* w2           = (const float*)d_in[8];
  const float* b2           = (const float*)d_in[9];

  float* out       = (float*)d_out;
  float* out_user  = out;
  float* out_item  = out + (size_t)NB * DIM;
  float* out_inter = out + (size_t)2 * NB * DIM;

  const size_t need = (size_t)NITEMS * DIM + 16384;
  if (ws_size >= need) {
    unsigned char* tbl8 = (unsigned char*)d_ws;
    unsigned char* w1f8 = tbl8 + (size_t)NITEMS * DIM;
    pre_kernel<<<GRP_BLKS + CONV_BLKS, 256, 0, stream>>>(user_ids, item_ids, user_table,
        item_table, fi, w1, tbl8, w1f8, out_item, out_inter);
    main_kernel_fp8<<<NB / 2, 256, 0, stream>>>(user_ids, user_history, user_table,
        tbl8, w1f8, b1, w2, b2, out_user);
  } else {
    main_fallback<<<NB / 4, 256, 0, stream>>>(user_ids, user_history, user_table,
        item_table, w1, b1, w2, b2, out_user);
    pre_kernel<<<GRP_BLKS, 256, 0, stream>>>(user_ids, item_ids, user_table,
        item_table, fi, w1, nullptr, nullptr, out_item, out_inter);
  }
}

// Round 9
// 101.460 us; speedup vs baseline: 1.2591x; 1.2591x over previous
//
#include <hip/hip_runtime.h>
#include <math.h>

#define NB      8192
#define HLEN    200
#define DIM     128
#define AH      64
#define NITEMS  100000
#define WTILES  7              // tiles per wave; 2 waves cover 14 (13 real + 1 masked)
#define GATHER_BLKS (NB / 2)   // 4096 blocks x 2 batch elems
#define INTER_BLKS  (NB / 4)   // 2048 blocks x 4 batch elems
#define CONV_BLKS 1024

typedef __attribute__((ext_vector_type(4))) float f32x4;
typedef __attribute__((ext_vector_type(2))) float f32x2;
typedef __attribute__((ext_vector_type(4))) int   i32x4;
typedef __attribute__((ext_vector_type(8))) short bf16x8;
typedef unsigned int uint;

__device__ __forceinline__ unsigned short f2bf(float f) {
  uint u = __float_as_uint(f);
  u += 0x7fffu + ((u >> 16) & 1u);
  return (unsigned short)(u >> 16);
}
__device__ __forceinline__ float bf2f(unsigned short h) {
  return __uint_as_float(((uint)h) << 16);
}
__device__ __forceinline__ long pick64(const i32x4& v, int h) {
  return (long)(unsigned)v[2 * h] | ((long)(unsigned)v[2 * h + 1] << 32);
}

// ---------------------------------------------------------------------------
// Convert kernel: item_table f32 -> fp8 e4m3 (row = 128B = one line) and
// w1 -> fp8 fragment table in the r2-verified layout:
//   w1f8[((((part*4+s)*4+nt)*16+m)*4+g)*8+j] = fp8(w1[kg][nt*16+m]),
//   kg = part*128 + (s>>1)*64 + g*16 + (s&1)*8 + j
// ---------------------------------------------------------------------------
__global__ __launch_bounds__(256)
void conv_kernel(const float* __restrict__ item_table,
                 const float* __restrict__ w1,
                 unsigned char* __restrict__ tbl8,
                 unsigned char* __restrict__ w1f8) {
  const long t0 = (long)blockIdx.x * 256 + threadIdx.x;
  const long total4 = (long)NITEMS * DIM / 4;
  const long stride = (long)CONV_BLKS * 256;
  for (long i = t0; i < total4; i += stride) {
    f32x4 v = ((const f32x4*)item_table)[i];
    int p = __builtin_amdgcn_cvt_pk_fp8_f32(v[0], v[1], 0, false);
    p     = __builtin_amdgcn_cvt_pk_fp8_f32(v[2], v[3], p, true);
    ((int*)tbl8)[i] = p;
  }
  if (t0 < 16384) {
    int L = (int)t0;
    int j = L & 7, gg = (L >> 3) & 3, mm = (L >> 5) & 15;
    int nt = (L >> 9) & 3, s = (L >> 11) & 3, part = (L >> 13) & 1;
    int kg = part * 128 + (s >> 1) * 64 + gg * 16 + (s & 1) * 8 + j;
    float v = w1[kg * AH + nt * 16 + mm];
    int pk = __builtin_amdgcn_cvt_pk_fp8_f32(v, v, 0, false);
    w1f8[L] = (unsigned char)(pk & 0xff);
  }
}

// ---------------------------------------------------------------------------
// Main kernel. Blocks [0, GATHER_BLKS): fp8 attention pooling, TWO waves per
// batch element (r2-verified body, 7 tiles each, partials combined via 1KB
// LDS + one barrier). Blocks [GATHER_BLKS, +INTER_BLKS): bilinear interaction
// + item copy (r7-verified body) — latency-bound gather blocks leave issue
// slots these dense blocks fill, hiding the ~9us of inter work.
// ---------------------------------------------------------------------------
__global__ __launch_bounds__(256)
void main_kernel_fp8(const int* __restrict__ user_ids,
                     const int* __restrict__ item_ids,
                     const int* __restrict__ user_history,
                     const float* __restrict__ user_table,
                     const float* __restrict__ item_table,
                     const float* __restrict__ fi,
                     const unsigned char* __restrict__ tbl8,
                     const unsigned char* __restrict__ w1f8,
                     const float* __restrict__ b1,
                     const float* __restrict__ w2,
                     const float* __restrict__ b2,
                     float* __restrict__ out_user,
                     float* __restrict__ out_item,
                     float* __restrict__ out_inter) {
  __shared__ __align__(16) unsigned char ldsbuf[35392];
  const int t = threadIdx.x;
  if (blockIdx.x < GATHER_BLKS) {
    // ================= gather branch: 2 b/block, 2 waves/b =================
    float* comb = (float*)ldsbuf;                 // [2][128]
    const int lane = t & 63;
    const int wave = t >> 6;
    const int bslot = wave >> 1;
    const int h = wave & 1;
    const int b = blockIdx.x * 2 + bslot;
    const int m = lane & 15;
    const int g = lane >> 4;

    const int uid = __builtin_amdgcn_readfirstlane(user_ids[b]);
    const float* urow = user_table + (long)uid * DIM;
    const int* hrow = user_history + (long)b * HLEN;

    // this wave's 7 history indices (rows (h*7+tt)*16 + m)
    int idxs[WTILES];
#pragma unroll
    for (int tt = 0; tt < WTILES; ++tt) {
      int row = (h * WTILES + tt) * 16 + m;
      idxs[tt] = (row < HLEN) ? hrow[row] : 0;
    }

    // gather ring: 4 buffers, distance 3 (r2-proven depth)
    i32x4 pa[4][2];
#define LOADT(T, BUF)                                                          \
    {                                                                          \
      const unsigned char* p_ = tbl8 + ((long)idxs[T] << 7) + g * 16;          \
      pa[BUF][0] = *(const i32x4*)p_;                                          \
      pa[BUF][1] = *(const i32x4*)(p_ + 64);                                   \
    }
    LOADT(0, 0) LOADT(1, 1) LOADT(2, 2)

    // u -> fp8 A-fragments (same (g,byte)->k map as history rows)
    i32x4 uf[2];
#pragma unroll
    for (int kb = 0; kb < 2; ++kb) {
      const float* up = urow + kb * 64 + g * 16;
      f32x4 q0 = *(const f32x4*)(up + 0);
      f32x4 q1 = *(const f32x4*)(up + 4);
      f32x4 q2 = *(const f32x4*)(up + 8);
      f32x4 q3 = *(const f32x4*)(up + 12);
      i32x4 d;
      d[0] = __builtin_amdgcn_cvt_pk_fp8_f32(q0[0], q0[1], 0, false);
      d[0] = __builtin_amdgcn_cvt_pk_fp8_f32(q0[2], q0[3], d[0], true);
      d[1] = __builtin_amdgcn_cvt_pk_fp8_f32(q1[0], q1[1], 0, false);
      d[1] = __builtin_amdgcn_cvt_pk_fp8_f32(q1[2], q1[3], d[1], true);
      d[2] = __builtin_amdgcn_cvt_pk_fp8_f32(q2[0], q2[1], 0, false);
      d[2] = __builtin_amdgcn_cvt_pk_fp8_f32(q2[2], q2[3], d[2], true);
      d[3] = __builtin_amdgcn_cvt_pk_fp8_f32(q3[0], q3[1], 0, false);
      d[3] = __builtin_amdgcn_cvt_pk_fp8_f32(q3[2], q3[3], d[3], true);
      uf[kb] = d;
    }

    const unsigned char* wtop = w1f8;
    const unsigned char* wbot = w1f8 + 8192;

    // u-projection via MFMA: ubreg = (u @ w1_top)[nt*16+m] + b1
    f32x4 accu[4];
#pragma unroll
    for (int nt = 0; nt < 4; ++nt) accu[nt] = (f32x4){0.f, 0.f, 0.f, 0.f};
#pragma unroll
    for (int s = 0; s < 4; ++s) {
      long a_s = pick64(uf[s >> 1], s & 1);
#pragma unroll
      for (int nt = 0; nt < 4; ++nt) {
        long bf = *(const long*)(wtop + ((s * 4 + nt) * 16 + m) * 32 + g * 8);
        accu[nt] = __builtin_amdgcn_mfma_f32_16x16x32_fp8_fp8(a_s, bf, accu[nt], 0, 0, 0);
      }
    }
    float ubreg[4], w2reg[4];
#pragma unroll
    for (int nt = 0; nt < 4; ++nt) {
      ubreg[nt] = accu[nt][0] + b1[nt * 16 + m];
      w2reg[nt] = w2[nt * 16 + m];
    }
    const float b2v = b2[0];

    // W1 bottom fragments, held in registers (16 x 8B)
    long bfr[4][4];
#pragma unroll
    for (int s = 0; s < 4; ++s)
#pragma unroll
      for (int nt = 0; nt < 4; ++nt)
        bfr[s][nt] = *(const long*)(wbot + ((s * 4 + nt) * 16 + m) * 32 + g * 8);

    float arep[32];
#pragma unroll
    for (int c = 0; c < 32; ++c) arep[c] = 0.f;

    // 7-tile pipelined loop (r2 body)
#pragma unroll
    for (int tt = 0; tt < WTILES; ++tt) {
      if (tt + 3 < WTILES) LOADT(tt + 3, (tt + 3) & 3)
      const int cb = tt & 3;

      f32x4 acc[4];
#pragma unroll
      for (int nt = 0; nt < 4; ++nt) acc[nt] = (f32x4){0.f, 0.f, 0.f, 0.f};
#pragma unroll
      for (int s = 0; s < 4; ++s) {
        long a_s = pick64(pa[cb][s >> 1], s & 1);
#pragma unroll
        for (int nt = 0; nt < 4; ++nt)
          acc[nt] = __builtin_amdgcn_mfma_f32_16x16x32_fp8_fp8(a_s, bfr[s][nt], acc[nt], 0, 0, 0);
      }

      float sums[4];
#pragma unroll
      for (int r = 0; r < 4; ++r) {
        float s = 0.f;
#pragma unroll
        for (int nt = 0; nt < 4; ++nt) {
          float hh = fmaxf(acc[nt][r] + ubreg[nt], 0.f);
          s = fmaf(hh, w2reg[nt], s);
        }
        s += __shfl_xor(s, 1);
        s += __shfl_xor(s, 2);
        s += __shfl_xor(s, 4);
        s += __shfl_xor(s, 8);
        sums[r] = s;
      }
      const int q = m & 3;
      float keep = (q == 0) ? sums[0] : (q == 1) ? sums[1] : (q == 2) ? sums[2] : sums[3];
      float sv = __shfl(keep, ((m >> 2) << 4) | m);
      float attw = 1.f / (1.f + __expf(-(sv + b2v)));
      if ((h * WTILES + tt) * 16 + m >= HLEN) attw = 0.f;

#pragma unroll
      for (int kb = 0; kb < 2; ++kb)
#pragma unroll
        for (int d = 0; d < 4; ++d) {
          f32x2 lo = __builtin_amdgcn_cvt_pk_f32_fp8(pa[cb][kb][d], false);
          f32x2 hi = __builtin_amdgcn_cvt_pk_f32_fp8(pa[cb][kb][d], true);
          const int base = kb * 16 + d * 4;
          arep[base + 0] = fmaf(attw, lo[0], arep[base + 0]);
          arep[base + 1] = fmaf(attw, lo[1], arep[base + 1]);
          arep[base + 2] = fmaf(attw, hi[0], arep[base + 2]);
          arep[base + 3] = fmaf(attw, hi[1], arep[base + 3]);
        }
    }
#undef LOADT

    // reduce over the 16 row-lanes of each group
#pragma unroll
    for (int c = 0; c < 32; ++c) {
      arep[c] += __shfl_xor(arep[c], 1);
      arep[c] += __shfl_xor(arep[c], 2);
      arep[c] += __shfl_xor(arep[c], 4);
      arep[c] += __shfl_xor(arep[c], 8);
    }

    // combine half-history partials: h==1 publishes, h==0 finalizes
    if (h == 1 && m == 0) {
#pragma unroll
      for (int kb = 0; kb < 2; ++kb)
#pragma unroll
        for (int i4 = 0; i4 < 4; ++i4)
#pragma unroll
          for (int qq = 0; qq < 4; ++qq)
            comb[bslot * 128 + kb * 64 + g * 16 + i4 * 4 + qq] = arep[kb * 16 + i4 * 4 + qq];
    }
    __syncthreads();
    if (h == 0 && m == 0) {
#pragma unroll
      for (int kb = 0; kb < 2; ++kb)
#pragma unroll
        for (int i4 = 0; i4 < 4; ++i4) {
          const int col = kb * 64 + g * 16 + i4 * 4;
          f32x4 uv = *(const f32x4*)(urow + col);
          f32x4 o;
#pragma unroll
          for (int qq = 0; qq < 4; ++qq)
            o[qq] = uv[qq] + arep[kb * 16 + i4 * 4 + qq] + comb[bslot * 128 + col + qq];
          *(f32x4*)(out_user + (long)b * DIM + col) = o;
        }
    }
  } else {
    // ================= inter branch: bilinear + item copy ==================
    unsigned short* fitb = (unsigned short*)ldsbuf;                 // [128*130]
    float (*u4)[DIM] = (float(*)[DIM])(ldsbuf + 33280);             // [4][128]
    float (*red)[4] = (float(*)[4])(ldsbuf + 35328);                // [4][4]
    for (int i = t; i < DIM * DIM; i += 256) {
      int d = i >> 7, e = i & 127;
      fitb[e * 130 + d] = f2bf(fi[i]);
    }
    const int col = t & 127;
    const int dh = t >> 7;
    const int lane = t & 63;
    const int wv = t >> 6;
    const int bb = (blockIdx.x - GATHER_BLKS) * 4;
    for (int i = t; i < 4 * DIM; i += 256) {
      int bi = i >> 7, d = i & 127;
      u4[bi][d] = user_table[(long)user_ids[bb + bi] * DIM + d];
    }
    __syncthreads();
    const unsigned short* fr = &fitb[col * 130 + dh * 64];
    float a0 = 0.f, a1 = 0.f, a2 = 0.f, a3 = 0.f;
#pragma unroll 4
    for (int d = 0; d < 64; d += 4) {
      float f0 = bf2f(fr[d]), f1 = bf2f(fr[d + 1]), f2 = bf2f(fr[d + 2]), f3 = bf2f(fr[d + 3]);
      f32x4 q0 = *(const f32x4*)&u4[0][dh * 64 + d];
      f32x4 q1 = *(const f32x4*)&u4[1][dh * 64 + d];
      f32x4 q2 = *(const f32x4*)&u4[2][dh * 64 + d];
      f32x4 q3 = *(const f32x4*)&u4[3][dh * 64 + d];
      a0 = fmaf(f0, q0[0], a0); a0 = fmaf(f1, q0[1], a0); a0 = fmaf(f2, q0[2], a0); a0 = fmaf(f3, q0[3], a0);
      a1 = fmaf(f0, q1[0], a1); a1 = fmaf(f1, q1[1], a1); a1 = fmaf(f2, q1[2], a1); a1 = fmaf(f3, q1[3], a1);
      a2 = fmaf(f0, q2[0], a2); a2 = fmaf(f1, q2[1], a2); a2 = fmaf(f2, q2[2], a2); a2 = fmaf(f3, q2[3], a2);
      a3 = fmaf(f0, q3[0], a3); a3 = fmaf(f1, q3[1], a3); a3 = fmaf(f2, q3[2], a3); a3 = fmaf(f3, q3[3], a3);
    }
    const float vv0 = item_table[(long)item_ids[bb + 0] * DIM + col];
    const float vv1 = item_table[(long)item_ids[bb + 1] * DIM + col];
    const float vv2 = item_table[(long)item_ids[bb + 2] * DIM + col];
    const float vv3 = item_table[(long)item_ids[bb + 3] * DIM + col];
    if (dh == 0) {
      out_item[(long)(bb + 0) * DIM + col] = vv0;
      out_item[(long)(bb + 1) * DIM + col] = vv1;
      out_item[(long)(bb + 2) * DIM + col] = vv2;
      out_item[(long)(bb + 3) * DIM + col] = vv3;
    }
    float p0 = a0 * vv0, p1 = a1 * vv1, p2 = a2 * vv2, p3 = a3 * vv3;
#pragma unroll
    for (int msk = 1; msk <= 32; msk <<= 1) {
      p0 += __shfl_xor(p0, msk);
      p1 += __shfl_xor(p1, msk);
      p2 += __shfl_xor(p2, msk);
      p3 += __shfl_xor(p3, msk);
    }
    if (lane == 0) { red[wv][0] = p0; red[wv][1] = p1; red[wv][2] = p2; red[wv][3] = p3; }
    __syncthreads();
    if (t < 4)
      out_inter[bb + t] = red[0][t] + red[1][t] + red[2][t] + red[3][t];
  }
}

// ---------------------------------------------------------------------------
// Fallback path (ws too small): r1 bf16-inline main + standalone inter.
// ---------------------------------------------------------------------------
__global__ __launch_bounds__(256)
void main_fallback(const int* __restrict__ user_ids,
                   const int* __restrict__ user_history,
                   const float* __restrict__ user_table,
                   const float* __restrict__ item_table,
                   const float* __restrict__ w1,
                   const float* __restrict__ b1,
                   const float* __restrict__ w2,
                   const float* __restrict__ b2,
                   float* __restrict__ out_user) {
  const int lane = threadIdx.x & 63;
  const int wave = threadIdx.x >> 6;
  const int b = blockIdx.x * 4 + wave;
  const int m = lane & 15, g = lane >> 4;
  const int uid = __builtin_amdgcn_readfirstlane(user_ids[b]);
  const float* urow = user_table + (long)uid * DIM;
  float upj = b1[lane];
#pragma unroll 8
  for (int d = 0; d < DIM; ++d) upj = fmaf(urow[d], w1[d * AH + lane], upj);
  bf16x8 bfr[4][4];
#pragma unroll
  for (int ks = 0; ks < 4; ++ks)
#pragma unroll
    for (int nt = 0; nt < 4; ++nt) {
      bf16x8 bv;
#pragma unroll
      for (int j = 0; j < 8; ++j)
        bv[j] = (short)f2bf(w1[(DIM + ks * 32 + g * 8 + j) * AH + nt * 16 + m]);
      bfr[ks][nt] = bv;
    }
  float ubreg[4], w2reg[4];
#pragma unroll
  for (int nt = 0; nt < 4; ++nt) {
    ubreg[nt] = __shfl(upj, nt * 16 + m);
    w2reg[nt] = w2[nt * 16 + m];
  }
  const float b2v = b2[0];
  float arep[32];
#pragma unroll
  for (int c = 0; c < 32; ++c) arep[c] = 0.f;
  const int* hrow = user_history + (long)b * HLEN;
  for (int tt = 0; tt < 13; ++tt) {
    const int row = tt * 16 + m;
    const int idx = (row < HLEN) ? hrow[row] : 0;
    bf16x8 a[4];
    const float* rp = item_table + (long)idx * DIM;
#pragma unroll
    for (int ks = 0; ks < 4; ++ks) {
      f32x4 lo = *(const f32x4*)(rp + ks * 32 + g * 8);
      f32x4 hi = *(const f32x4*)(rp + ks * 32 + g * 8 + 4);
      bf16x8 av;
      av[0] = (short)f2bf(lo[0]); av[1] = (short)f2bf(lo[1]);
      av[2] = (short)f2bf(lo[2]); av[3] = (short)f2bf(lo[3]);
      av[4] = (short)f2bf(hi[0]); av[5] = (short)f2bf(hi[1]);
      av[6] = (short)f2bf(hi[2]); av[7] = (short)f2bf(hi[3]);
      a[ks] = av;
    }
    f32x4 acc[4];
#pragma unroll
    for (int nt = 0; nt < 4; ++nt) acc[nt] = (f32x4){0.f, 0.f, 0.f, 0.f};
#pragma unroll
    for (int ks = 0; ks < 4; ++ks)
#pragma unroll
      for (int nt = 0; nt < 4; ++nt)
        acc[nt] = __builtin_amdgcn_mfma_f32_16x16x32_bf16(a[ks], bfr[ks][nt], acc[nt], 0, 0, 0);
    float sums[4];
#pragma unroll
    for (int r = 0; r < 4; ++r) {
      float s = 0.f;
#pragma unroll
      for (int nt = 0; nt < 4; ++nt) {
        float hh = fmaxf(acc[nt][r] + ubreg[nt], 0.f);
        s = fmaf(hh, w2reg[nt], s);
      }
      s += __shfl_xor(s, 1); s += __shfl_xor(s, 2);
      s += __shfl_xor(s, 4); s += __shfl_xor(s, 8);
      sums[r] = s;
    }
    const int q = m & 3;
    float keep = (q == 0) ? sums[0] : (q == 1) ? sums[1] : (q == 2) ? sums[2] : sums[3];
    float sv = __shfl(keep, ((m >> 2) << 4) | m);
    float attw = 1.f / (1.f + __expf(-(sv + b2v)));
    if (row >= HLEN) attw = 0.f;
#pragma unroll
    for (int ks = 0; ks < 4; ++ks)
#pragma unroll
      for (int j = 0; j < 8; ++j)
        arep[ks * 8 + j] = fmaf(attw, bf2f((unsigned short)a[ks][j]), arep[ks * 8 + j]);
  }
#pragma unroll
  for (int c = 0; c < 32; ++c) {
    arep[c] += __shfl_xor(arep[c], 1);
    arep[c] += __shfl_xor(arep[c], 2);
    arep[c] += __shfl_xor(arep[c], 4);
    arep[c] += __shfl_xor(arep[c], 8);
  }
  if (m == 0) {
#pragma unroll
    for (int ks = 0; ks < 4; ++ks)
#pragma unroll
      for (int j = 0; j < 8; ++j) {
        const int col = ks * 32 + g * 8 + j;
        out_user[(long)b * DIM + col] = urow[col] + arep[ks * 8 + j];
      }
  }
}

__global__ __launch_bounds__(256)
void inter_kernel(const int* __restrict__ user_ids,
                  const int* __restrict__ item_ids,
                  const float* __restrict__ user_table,
                  const float* __restrict__ item_table,
                  const float* __restrict__ fi,
                  float* __restrict__ out_item,
                  float* __restrict__ out_inter) {
  __shared__ unsigned short fitb[DIM * 130];
  __shared__ float u4[4][DIM];
  __shared__ float red[4][4];
  const int t = threadIdx.x;
  for (int i = t; i < DIM * DIM; i += 256) {
    int d = i >> 7, e = i & 127;
    fitb[e * 130 + d] = f2bf(fi[i]);
  }
  const int col = t & 127;
  const int dh = t >> 7;
  const int lane = t & 63;
  const int wv = t >> 6;
  const int bb = blockIdx.x * 4;
  for (int i = t; i < 4 * DIM; i += 256) {
    int bi = i >> 7, d = i & 127;
    u4[bi][d] = user_table[(long)user_ids[bb + bi] * DIM + d];
  }
  __syncthreads();
  const unsigned short* fr = &fitb[col * 130 + dh * 64];
  float a0 = 0.f, a1 = 0.f, a2 = 0.f, a3 = 0.f;
#pragma unroll 4
  for (int d = 0; d < 64; d += 4) {
    float f0 = bf2f(fr[d]), f1 = bf2f(fr[d + 1]), f2 = bf2f(fr[d + 2]), f3 = bf2f(fr[d + 3]);
    f32x4 q0 = *(const f32x4*)&u4[0][dh * 64 + d];
    f32x4 q1 = *(const f32x4*)&u4[1][dh * 64 + d];
    f32x4 q2 = *(const f32x4*)&u4[2][dh * 64 + d];
    f32x4 q3 = *(const f32x4*)&u4[3][dh * 64 + d];
    a0 = fmaf(f0, q0[0], a0); a0 = fmaf(f1, q0[1], a0); a0 = fmaf(f2, q0[2], a0); a0 = fmaf(f3, q0[3], a0);
    a1 = fmaf(f0, q1[0], a1); a1 = fmaf(f1, q1[1], a1); a1 = fmaf(f2, q1[2], a1); a1 = fmaf(f3, q1[3], a1);
    a2 = fmaf(f0, q2[0], a2); a2 = fmaf(f1, q2[1], a2); a2 = fmaf(f2, q2[2], a2); a2 = fmaf(f3, q2[3], a2);
    a3 = fmaf(f0, q3[0], a3); a3 = fmaf(f1, q3[1], a3); a3 = fmaf(f2, q3[2], a3); a3 = fmaf(f3, q3[3], a3);
  }
  const float vv0 = item_table[(long)item_ids[bb + 0] * DIM + col];
  const float vv1 = item_table[(long)item_ids[bb + 1] * DIM + col];
  const float vv2 = item_table[(long)item_ids[bb + 2] * DIM + col];
  const float vv3 = item_table[(long)item_ids[bb + 3] * DIM + col];
  if (dh == 0) {
    out_item[(long)(bb + 0) * DIM + col] = vv0;
    out_item[(long)(bb + 1) * DIM + col] = vv1;
    out_item[(long)(bb + 2) * DIM + col] = vv2;
    out_item[(long)(bb + 3) * DIM + col] = vv3;
  }
  float p0 = a0 * vv0, p1 = a1 * vv1, p2 = a2 * vv2, p3 = a3 * vv3;
#pragma unroll
  for (int msk = 1; msk <= 32; msk <<= 1) {
    p0 += __shfl_xor(p0, msk);
    p1 += __shfl_xor(p1, msk);
    p2 += __shfl_xor(p2, msk);
    p3 += __shfl_xor(p3, msk);
  }
  if (lane == 0) { red[wv][0] = p0; red[wv][1] = p1; red[wv][2] = p2; red[wv][3] = p3; }
  __syncthreads();
  if (t < 4)
    out_inter[bb + t] = red[0][t] + red[1][t] + red[2][t] + red[3][t];
}

// ---------------------------------------------------------------------------
extern "C" void kernel_launch(void* const* d_in, const int* in_sizes, int n_in,
                              void* d_out, int out_size, void* d_ws, size_t ws_size,
                              hipStream_t stream) {
  const int*   user_ids     = (const int*)d_in[0];
  const int*   item_ids     = (const int*)d_in[1];
  const int*   user_history = (const int*)d_in[2];
  const float* user_table   = (const float*)d_in[3];
  const float* item_table   = (const float*)d_in[4];
  const float* fi           = (const float*)d_in[5];
  const float* w1           = (const float*)d_in[6];
  const float* b1           = (const float*)d_in[7];
  const float* w2           = (const float*)d_in[8];
  const float* b2           = (const float*)d_in[9];

  float* out       = (float*)d_out;
  float* out_user  = out;
  float* out_item  = out + (size_t)NB * DIM;
  float* out_inter = out + (size_t)2 * NB * DIM;

  const size_t need = (size_t)NITEMS * DIM + 16384;
  if (ws_size >= need) {
    unsigned char* tbl8 = (unsigned char*)d_ws;
    unsigned char* w1f8 = tbl8 + (size_t)NITEMS * DIM;
    conv_kernel<<<CONV_BLKS, 256, 0, stream>>>(item_table, w1, tbl8, w1f8);
    main_kernel_fp8<<<GATHER_BLKS + INTER_BLKS, 256, 0, stream>>>(user_ids, item_ids,
        user_history, user_table, item_table, fi, tbl8, w1f8, b1, w2, b2,
        out_user, out_item, out_inter);
  } else {
    main_fallback<<<NB / 4, 256, 0, stream>>>(user_ids, user_history, user_table,
        item_table, w1, b1, w2, b2, out_user);
    inter_kernel<<<NB / 4, 256, 0, stream>>>(user_ids, item_ids, user_table,
        item_table, fi, out_item, out_inter);
  }
}